// Round 1
// baseline (420.243 us; speedup 1.0000x reference)
//
#include <hip/hip_runtime.h>
#include <stdint.h>

#define NBITS  8
#define SLICE  1024
#define OUTF   512
#define INF    8192
#define TOPK   32
#define BATCHN 4096

// ---------------------------------------------------------------------------
// prep: pack b = (W>=0)+(Wm>=0) in {0,1,2} as 4-bit fields, 8 cols per u32.
// Word w of row r holds columns {w + 64*i}, field i.  (stride-64 interleave so
// the main kernel's LDS scatter of per-column sums is bank-conflict free.)
// Also zeroes the latent_group counters.
// ---------------------------------------------------------------------------
__global__ __launch_bounds__(256) void prep_kernel(
    const float* __restrict__ W, const float* __restrict__ Wm,
    uint32_t* __restrict__ tbl, int* __restrict__ cnts)
{
  int tid = blockIdx.x * blockDim.x + threadIdx.x;   // 8192*64 threads
  if (tid < NBITS) cnts[tid] = 0;
  int r = tid >> 6;        // row 0..8191  (= n*1024 + s)
  int w = tid & 63;        // word 0..63
  const float* wr = W  + (size_t)r * OUTF;
  const float* mr = Wm + (size_t)r * OUTF;
  uint32_t word = 0;
#pragma unroll
  for (int i = 0; i < 8; ++i) {
    int col = w + 64 * i;
    uint32_t b = (wr[col] >= 0.0f ? 1u : 0u) + (mr[col] >= 0.0f ? 1u : 0u);
    word |= b << (4 * i);
  }
  tbl[tid] = word;
}

// ---------------------------------------------------------------------------
// main: one block per batch row. 8 waves; wave n handles bit-slice n:
//   - exact top-32 of 1024 (binary search on sortable keys, ballot counting,
//     jax.lax.top_k tie-break: lower index first)
//   - gather 32 rows of packed table, 4-bit packed accumulate (P/N split)
//   - per-column contrib -> LDS, then block-wide cumsum over bits + store
// ---------------------------------------------------------------------------
__global__ __launch_bounds__(512) void main_kernel(
    const float* __restrict__ latent,
    const uint32_t* __restrict__ tbl,
    float* __restrict__ out, int* __restrict__ cnts)
{
  __shared__ uint32_t sel[NBITS][TOPK];     // (idx<<2) | (sgn+1)
  __shared__ float    sums[NBITS][OUTF];    // per-bit contrib, per column

  const int b    = blockIdx.x;
  const int wv   = threadIdx.x >> 6;        // bit index n
  const int lane = threadIdx.x & 63;

  // ---- load 16 contiguous values of this wave's slice --------------------
  const float4* src =
      (const float4*)(latent + (size_t)b * INF + (size_t)wv * SLICE + lane * 16);
  float v[16];
#pragma unroll
  for (int q = 0; q < 4; ++q) {
    float4 f = src[q];
    v[4*q+0] = f.x; v[4*q+1] = f.y; v[4*q+2] = f.z; v[4*q+3] = f.w;
  }
  uint32_t key[16];
#pragma unroll
  for (int j = 0; j < 16; ++j) {
    uint32_t u = __float_as_uint(v[j]);
    uint32_t m = ((uint32_t)((int32_t)u >> 31)) | 0x80000000u;
    key[j] = u ^ m;                          // monotone total order
  }

  // ---- binary search for T = 32nd-largest key (exact) --------------------
  uint32_t lo = 0u, hi = 0xFFFFFFFFu;
  while (lo < hi) {
    uint32_t d   = hi - lo;
    uint32_t mid = lo + (d >> 1) + (d & 1u);   // upper mid, no overflow
    int cnt = 0;
#pragma unroll
    for (int j = 0; j < 16; ++j)
      cnt += (int)__popcll(__ballot(key[j] >= mid));
    if (cnt >= TOPK) lo = mid; else hi = mid - 1u;
  }
  const uint32_t T = lo;

  // ---- selection with stable (lowest-index-first) tie-break --------------
  int cgt = 0, ceq = 0;
#pragma unroll
  for (int j = 0; j < 16; ++j) { cgt += (key[j] > T); ceq += (key[j] == T); }
  int packed = (cgt << 16) | ceq;
  int sc = packed;
#pragma unroll
  for (int dd = 1; dd < 64; dd <<= 1) {
    int t = __shfl_up(sc, dd);
    if (lane >= dd) sc += t;
  }
  int tot     = __shfl(sc, 63);
  int total_g = tot >> 16;                 // # strictly greater than T (<32)
  int nties   = TOPK - total_g;            // ties to take, lowest index first
  int excl    = sc - packed;
  int posg    = excl >> 16;
  int pose    = excl & 0xFFFF;

  int cnz = 0;
#pragma unroll
  for (int j = 0; j < 16; ++j) {
    uint32_t kk = key[j];
    bool isgt   = kk > T;
    bool iseq   = (kk == T);
    bool takeeq = iseq && (pose < nties);
    int  idx    = lane * 16 + j;
    int  sgn    = (v[j] > 0.0f) - (v[j] < 0.0f);
    uint32_t code = ((uint32_t)idx << 2) | (uint32_t)(sgn + 1);
    if (isgt)        sel[wv][posg++]          = code;
    else if (takeeq) sel[wv][total_g + pose]  = code;
    unsigned long long bm = __ballot((isgt || takeeq) && (sgn != 0));
    cnz += (int)__popcll(bm);                // uniform across wave
    pose += iseq;
  }
  if (lane == 0) atomicAdd(&cnts[wv], cnz);

  // ---- gather + packed accumulate ----------------------------------------
  // prefetch the 32 selected codes into registers (broadcast LDS reads)
  uint32_t ecode[TOPK];
  {
    const uint4* sp = (const uint4*)sel[wv];
#pragma unroll
    for (int q = 0; q < TOPK / 4; ++q) {
      uint4 e4 = sp[q];
      ecode[4*q+0] = e4.x; ecode[4*q+1] = e4.y;
      ecode[4*q+2] = e4.z; ecode[4*q+3] = e4.w;
    }
  }

  uint32_t accP0 = 0, accP1 = 0, accN0 = 0, accN1 = 0;
  uint32_t tmpP = 0, tmpN = 0;
  int cntP = 0, cntN = 0, inchunk = 0;
  const uint32_t* rowbase = tbl + (size_t)wv * SLICE * 64 + lane;
#pragma unroll
  for (int j = 0; j < TOPK; ++j) {
    uint32_t e   = ecode[j];
    int      sgn = (int)(e & 3u) - 1;
    uint32_t idx = e >> 2;
    uint32_t wrd = rowbase[(size_t)idx * 64];
    if (sgn > 0)      { tmpP += wrd; cntP++; }
    else if (sgn < 0) { tmpN += wrd; cntN++; }
    if (++inchunk == 7 || j == TOPK - 1) {   // 7*2=14 < 16: no field overflow
      accP0 += tmpP & 0x0F0F0F0Fu; accP1 += (tmpP >> 4) & 0x0F0F0F0Fu;
      accN0 += tmpN & 0x0F0F0F0Fu; accN1 += (tmpN >> 4) & 0x0F0F0F0Fu;
      tmpP = 0; tmpN = 0; inchunk = 0;
    }
  }

  // ---- unpack per-column sums: S = 2*(Pb - Nb) - 2*(cntP - cntN) ----------
  const float scale_n = 1.0f / (float)(1 << wv);   // 2^(6-n) * 4/256 = 2^-n
  const int   corr    = 2 * (cntP - cntN);
#pragma unroll
  for (int i2 = 0; i2 < 4; ++i2) {
    int p0 = (int)((accP0 >> (8 * i2)) & 0xFFu);
    int q0 = (int)((accN0 >> (8 * i2)) & 0xFFu);
    int p1 = (int)((accP1 >> (8 * i2)) & 0xFFu);
    int q1 = (int)((accN1 >> (8 * i2)) & 0xFFu);
    int s0 = 2 * (p0 - q0) - corr;   // col = lane + 128*i2
    int s1 = 2 * (p1 - q1) - corr;   // col = lane + 128*i2 + 64
    sums[wv][lane + 128 * i2]      = scale_n * (float)s0;
    sums[wv][lane + 128 * i2 + 64] = scale_n * (float)s1;
  }

  __syncthreads();

  // ---- cumsum over bits, store result[n][b][col] --------------------------
  const int col = threadIdx.x;               // 0..511
  float racc = 0.0f;
  float* obase = out + 8 + (size_t)b * OUTF + col;
#pragma unroll
  for (int n2 = 0; n2 < NBITS; ++n2) {
    racc += sums[n2][col];
    obase[(size_t)n2 * BATCHN * OUTF] = racc;
  }
}

// ---------------------------------------------------------------------------
// finalize latent_group = counts / BATCH
// ---------------------------------------------------------------------------
__global__ void fin_kernel(const int* __restrict__ cnts, float* __restrict__ out)
{
  int i = threadIdx.x;
  if (i < NBITS) out[i] = (float)cnts[i] * (1.0f / (float)BATCHN);
}

extern "C" void kernel_launch(void* const* d_in, const int* in_sizes, int n_in,
                              void* d_out, int out_size, void* d_ws, size_t ws_size,
                              hipStream_t stream)
{
  const float* latent = (const float*)d_in[0];
  const float* W      = (const float*)d_in[1];
  const float* Wm     = (const float*)d_in[2];
  float* out = (float*)d_out;

  int*      cnts = (int*)d_ws;                         // 8 ints
  uint32_t* tbl  = (uint32_t*)((char*)d_ws + 256);     // 8192*64 u32 = 2 MB

  prep_kernel<<<(INF * 64) / 256, 256, 0, stream>>>(W, Wm, tbl, cnts);
  main_kernel<<<BATCHN, 512, 0, stream>>>(latent, tbl, out, cnts);
  fin_kernel<<<1, 64, 0, stream>>>(cnts, out);
}

// Round 2
// 125.323 us; speedup vs baseline: 3.3533x; 3.3533x over previous
//
#include <hip/hip_runtime.h>
#include <stdint.h>

#define NBITS  8
#define SLICE  1024
#define OUTF   512
#define INF    8192
#define TOPK   32
#define BATCHN 4096

// ---------------------------------------------------------------------------
// prep: pack b = (W>=0)+(Wm>=0) in {0,1,2} as 4-bit fields, 8 cols per u32.
// Word w of row r holds columns {w + 64*i}, field i.
// ---------------------------------------------------------------------------
__global__ __launch_bounds__(256) void prep_kernel(
    const float* __restrict__ W, const float* __restrict__ Wm,
    uint32_t* __restrict__ tbl)
{
  int tid = blockIdx.x * blockDim.x + threadIdx.x;   // 8192*64 threads
  int r = tid >> 6;        // row 0..8191  (= n*1024 + s)
  int w = tid & 63;        // word 0..63
  const float* wr = W  + (size_t)r * OUTF;
  const float* mr = Wm + (size_t)r * OUTF;
  uint32_t word = 0;
#pragma unroll
  for (int i = 0; i < 8; ++i) {
    int col = w + 64 * i;
    uint32_t b = (wr[col] >= 0.0f ? 1u : 0u) + (mr[col] >= 0.0f ? 1u : 0u);
    word |= b << (4 * i);
  }
  tbl[tid] = word;
}

// ---------------------------------------------------------------------------
// main: one block per batch row. 8 waves; wave n handles bit-slice n:
//   - exact top-32 of 1024 (binary search on sortable keys, ballot counting,
//     jax.lax.top_k tie-break: lower index first)
//   - gather 32 rows of packed table (batched loads for MLP), 4-bit packed
//     accumulate (P/N split)
//   - per-column contrib -> LDS, block-wide cumsum over bits, store
//   - per-wave nonzero count -> partial[] (no global atomics!)
// ---------------------------------------------------------------------------
__global__ __launch_bounds__(512) void main_kernel(
    const float* __restrict__ latent,
    const uint32_t* __restrict__ tbl,
    float* __restrict__ out, int* __restrict__ partial)
{
  __shared__ uint32_t sel[NBITS][TOPK];     // (idx<<2) | (sgn+1)
  __shared__ float    sums[NBITS][OUTF];    // per-bit contrib, per column

  const int b    = blockIdx.x;
  const int wv   = threadIdx.x >> 6;        // bit index n
  const int lane = threadIdx.x & 63;

  // ---- load 16 contiguous values of this wave's slice --------------------
  const float4* src =
      (const float4*)(latent + (size_t)b * INF + (size_t)wv * SLICE + lane * 16);
  float v[16];
#pragma unroll
  for (int q = 0; q < 4; ++q) {
    float4 f = src[q];
    v[4*q+0] = f.x; v[4*q+1] = f.y; v[4*q+2] = f.z; v[4*q+3] = f.w;
  }
  uint32_t key[16];
#pragma unroll
  for (int j = 0; j < 16; ++j) {
    uint32_t u = __float_as_uint(v[j]);
    uint32_t m = ((uint32_t)((int32_t)u >> 31)) | 0x80000000u;
    key[j] = u ^ m;                          // monotone total order
  }

  // ---- binary search for T = 32nd-largest key (exact) --------------------
  uint32_t lo = 0u, hi = 0xFFFFFFFFu;
  while (lo < hi) {
    uint32_t d   = hi - lo;
    uint32_t mid = lo + (d >> 1) + (d & 1u);   // upper mid, no overflow
    int cnt = 0;
#pragma unroll
    for (int j = 0; j < 16; ++j)
      cnt += (int)__popcll(__ballot(key[j] >= mid));
    if (cnt >= TOPK) lo = mid; else hi = mid - 1u;
  }
  const uint32_t T = lo;

  // ---- selection with stable (lowest-index-first) tie-break --------------
  int cgt = 0, ceq = 0;
#pragma unroll
  for (int j = 0; j < 16; ++j) { cgt += (key[j] > T); ceq += (key[j] == T); }
  int packed = (cgt << 16) | ceq;
  int sc = packed;
#pragma unroll
  for (int dd = 1; dd < 64; dd <<= 1) {
    int t = __shfl_up(sc, dd);
    if (lane >= dd) sc += t;
  }
  int tot     = __shfl(sc, 63);
  int total_g = tot >> 16;                 // # strictly greater than T (<32)
  int nties   = TOPK - total_g;            // ties to take, lowest index first
  int excl    = sc - packed;
  int posg    = excl >> 16;
  int pose    = excl & 0xFFFF;

  int cnz = 0;
#pragma unroll
  for (int j = 0; j < 16; ++j) {
    uint32_t kk = key[j];
    bool isgt   = kk > T;
    bool iseq   = (kk == T);
    bool takeeq = iseq && (pose < nties);
    int  idx    = lane * 16 + j;
    int  sgn    = (v[j] > 0.0f) - (v[j] < 0.0f);
    uint32_t code = ((uint32_t)idx << 2) | (uint32_t)(sgn + 1);
    if (isgt)        sel[wv][posg++]          = code;
    else if (takeeq) sel[wv][total_g + pose]  = code;
    unsigned long long bm = __ballot((isgt || takeeq) && (sgn != 0));
    cnz += (int)__popcll(bm);                // uniform across wave
    pose += iseq;
  }
  if (lane == 0) partial[wv * BATCHN + b] = cnz;   // contention-free

  // ---- gather + packed accumulate ----------------------------------------
  // prefetch the 32 selected codes into registers (broadcast LDS reads)
  uint32_t ecode[TOPK];
  {
    const uint4* sp = (const uint4*)sel[wv];
#pragma unroll
    for (int q = 0; q < TOPK / 4; ++q) {
      uint4 e4 = sp[q];
      ecode[4*q+0] = e4.x; ecode[4*q+1] = e4.y;
      ecode[4*q+2] = e4.z; ecode[4*q+3] = e4.w;
    }
  }

  uint32_t accP0 = 0, accP1 = 0, accN0 = 0, accN1 = 0;
  int cntP = 0, cntN = 0;
  const uint32_t* rowbase = tbl + (size_t)wv * SLICE * 64 + lane;
#pragma unroll
  for (int half = 0; half < 2; ++half) {
    // batch the 16 gather loads so they are all in flight at once (MLP)
    uint32_t wrd[16];
#pragma unroll
    for (int j = 0; j < 16; ++j)
      wrd[j] = rowbase[(size_t)(ecode[half * 16 + j] >> 2) * 64];

    uint32_t tmpP = 0, tmpN = 0;
    int inchunk = 0;
#pragma unroll
    for (int j = 0; j < 16; ++j) {
      int sgn = (int)(ecode[half * 16 + j] & 3u) - 1;
      if (sgn > 0)      { tmpP += wrd[j]; cntP++; }
      else if (sgn < 0) { tmpN += wrd[j]; cntN++; }
      if (++inchunk == 7 || j == 15) {       // <=7 words: 4-bit fields safe
        accP0 += tmpP & 0x0F0F0F0Fu; accP1 += (tmpP >> 4) & 0x0F0F0F0Fu;
        accN0 += tmpN & 0x0F0F0F0Fu; accN1 += (tmpN >> 4) & 0x0F0F0F0Fu;
        tmpP = 0; tmpN = 0; inchunk = 0;
      }
    }
  }

  // ---- unpack per-column sums: S = 2*(Pb - Nb) - 2*(cntP - cntN) ----------
  const float scale_n = 1.0f / (float)(1 << wv);   // 2^(6-n) * 4/256 = 2^-n
  const int   corr    = 2 * (cntP - cntN);
#pragma unroll
  for (int i2 = 0; i2 < 4; ++i2) {
    int p0 = (int)((accP0 >> (8 * i2)) & 0xFFu);
    int q0 = (int)((accN0 >> (8 * i2)) & 0xFFu);
    int p1 = (int)((accP1 >> (8 * i2)) & 0xFFu);
    int q1 = (int)((accN1 >> (8 * i2)) & 0xFFu);
    int s0 = 2 * (p0 - q0) - corr;   // col = lane + 128*i2
    int s1 = 2 * (p1 - q1) - corr;   // col = lane + 128*i2 + 64
    sums[wv][lane + 128 * i2]      = scale_n * (float)s0;
    sums[wv][lane + 128 * i2 + 64] = scale_n * (float)s1;
  }

  __syncthreads();

  // ---- cumsum over bits, store result[n][b][col] --------------------------
  const int col = threadIdx.x;               // 0..511
  float racc = 0.0f;
  float* obase = out + 8 + (size_t)b * OUTF + col;
#pragma unroll
  for (int n2 = 0; n2 < NBITS; ++n2) {
    racc += sums[n2][col];
    obase[(size_t)n2 * BATCHN * OUTF] = racc;
  }
}

// ---------------------------------------------------------------------------
// finalize: latent_group[n] = (sum_b partial[n][b]) / BATCH
// 8 waves, wave n reduces its 4096 ints (coalesced), shuffle-reduce, store.
// ---------------------------------------------------------------------------
__global__ __launch_bounds__(512) void fin_kernel(
    const int* __restrict__ partial, float* __restrict__ out)
{
  const int wv   = threadIdx.x >> 6;
  const int lane = threadIdx.x & 63;
  const int* p = partial + wv * BATCHN;
  int s = 0;
#pragma unroll
  for (int k = 0; k < BATCHN / 64; ++k)
    s += p[lane + 64 * k];
#pragma unroll
  for (int d = 32; d >= 1; d >>= 1)
    s += __shfl_down(s, d);
  if (lane == 0) out[wv] = (float)s * (1.0f / (float)BATCHN);
}

extern "C" void kernel_launch(void* const* d_in, const int* in_sizes, int n_in,
                              void* d_out, int out_size, void* d_ws, size_t ws_size,
                              hipStream_t stream)
{
  const float* latent = (const float*)d_in[0];
  const float* W      = (const float*)d_in[1];
  const float* Wm     = (const float*)d_in[2];
  float* out = (float*)d_out;

  int*      partial = (int*)d_ws;                          // 8*4096 ints = 128 KB
  uint32_t* tbl     = (uint32_t*)((char*)d_ws + 131072);   // 8192*64 u32 = 2 MB

  prep_kernel<<<(INF * 64) / 256, 256, 0, stream>>>(W, Wm, tbl);
  main_kernel<<<BATCHN, 512, 0, stream>>>(latent, tbl, out, partial);
  fin_kernel<<<1, 512, 0, stream>>>(partial, out);
}

// Round 3
// 90.094 us; speedup vs baseline: 4.6645x; 1.3910x over previous
//
#include <hip/hip_runtime.h>
#include <stdint.h>

#define NBITS  8
#define SLICE  1024
#define OUTF   512
#define INF    8192
#define TOPK   32
#define BATCHN 4096

#define ROWS    INF                    // 8192 table rows (n*1024+s), 64 words each
#define DUMMY_W (ROWS * 64)            // dummy row (fields=1 -> contributes 0)
#define TBL2_W  ((ROWS + 1) * 64)      // complement table (fields = 2-b)

// ---------------------------------------------------------------------------
// prep: pack b = (W>=0)+(Wm>=0) in {0,1,2} as 4-bit fields, 8 cols per u32.
// Word w of row r holds columns {w + 64*i}, field i.  Also writes the
// complement table (2-b, used to fold negative latent signs into the gather)
// and a dummy row of 1-fields (zero contribution, used for sign==0 entries).
// ---------------------------------------------------------------------------
__global__ __launch_bounds__(256) void prep_kernel(
    const float* __restrict__ W, const float* __restrict__ Wm,
    uint32_t* __restrict__ tbl)
{
  int tid = blockIdx.x * blockDim.x + threadIdx.x;   // 8192*64 threads
  int r = tid >> 6;        // row 0..8191  (= n*1024 + s)
  int w = tid & 63;        // word 0..63
  const float* wr = W  + (size_t)r * OUTF;
  const float* mr = Wm + (size_t)r * OUTF;
  uint32_t word = 0;
#pragma unroll
  for (int i = 0; i < 8; ++i) {
    int col = w + 64 * i;
    uint32_t b = (wr[col] >= 0.0f ? 1u : 0u) + (mr[col] >= 0.0f ? 1u : 0u);
    word |= b << (4 * i);
  }
  tbl[tid] = word;
  tbl[TBL2_W + tid] = 0x22222222u - word;   // fields 2-b (no borrows: b<=2)
  if (tid < 64) tbl[DUMMY_W + tid] = 0x11111111u;
}

// ---------------------------------------------------------------------------
// main: one block per batch row, 8 waves; wave n handles bit-slice n.
//  - exact top-32 threshold: binary search, per-lane VALU count + 5-ballot
//    bit-serial wave sum (low SALU), early exit when count==32 (exact).
//  - selection writes sign-folded table row offsets (P / complement / dummy).
//  - gather: 32 unconditional load+add, packed 4-bit accumulate.
//  - per-column S = 2*field_sum - 64, cumsum over bits via LDS, store.
// ---------------------------------------------------------------------------
__global__ __launch_bounds__(512, 4) void main_kernel(
    const float* __restrict__ latent,
    const uint32_t* __restrict__ tbl,
    float* __restrict__ out, int* __restrict__ partial)
{
  __shared__ uint32_t sel[NBITS][TOPK];     // table row word-offsets
  __shared__ float    sums[NBITS][OUTF];    // per-bit contrib, per column

  const int b    = blockIdx.x;
  const int wv   = threadIdx.x >> 6;        // bit index n
  const int lane = threadIdx.x & 63;

  // ---- load 16 contiguous values of this wave's slice, map to sort keys ---
  const float4* src =
      (const float4*)(latent + (size_t)b * INF + (size_t)wv * SLICE + lane * 16);
  uint32_t key[16];
#pragma unroll
  for (int q = 0; q < 4; ++q) {
    float4 f = src[q];
    float vv[4] = {f.x, f.y, f.z, f.w};
#pragma unroll
    for (int t = 0; t < 4; ++t) {
      uint32_t u = __float_as_uint(vv[t]);
      uint32_t m = ((uint32_t)((int32_t)u >> 31)) | 0x80000000u;
      key[4*q+t] = u ^ m;                    // monotone total order
    }
  }
  // sign from key:  v>0 <=> key>0x80000000 ; v<0 <=> key<0x7FFFFFFF
  // zero keys: 0x80000000 (+0), 0x7FFFFFFF (-0)

  // ---- binary search for threshold (exact, early-exit) --------------------
  uint32_t T;
  {
    uint32_t lo = 0u, hi = 0xFFFFFFFFu;
    bool done = false;
    while (lo < hi) {
      uint32_t d   = hi - lo;
      uint32_t mid = lo + (d >> 1) + (d & 1u);   // upper mid
      int c = 0;
#pragma unroll
      for (int j = 0; j < 16; ++j) c += (key[j] >= mid) ? 1 : 0;
      int cnt = 0;
#pragma unroll
      for (int bb = 0; bb < 5; ++bb)
        cnt += (int)__popcll(__ballot((c >> bb) & 1)) << bb;
      if (cnt == TOPK) { T = mid - 1u; done = true; break; }  // exact set!
      if (cnt > TOPK) lo = mid; else hi = mid - 1u;
    }
    if (!done) T = lo;
  }

  // ---- counts + stable (lowest-index-first) tie positions ----------------
  int cgt = 0, ceq = 0;
#pragma unroll
  for (int j = 0; j < 16; ++j) { cgt += (key[j] > T); ceq += (key[j] == T); }
  int packed = (cgt << 16) | ceq;
  int sc = packed;
#pragma unroll
  for (int dd = 1; dd < 64; dd <<= 1) {
    int t = __shfl_up(sc, dd);
    if (lane >= dd) sc += t;
  }
  int tot     = __shfl(sc, 63);
  int total_g = tot >> 16;                 // # strictly greater than T (<=32)
  int nties   = TOPK - total_g;            // ties to take, lowest index first
  int excl    = sc - packed;
  int posg    = excl >> 16;
  int pose    = excl & 0xFFFF;

  // ---- selection: write sign-folded row offsets ---------------------------
  const uint32_t pbase = ((uint32_t)wv << 16) + ((uint32_t)lane << 10);
  int cnz_l = 0;
#pragma unroll
  for (int j = 0; j < 16; ++j) {
    uint32_t kk = key[j];
    bool isgt   = kk > T;
    bool iseq   = (kk == T);
    bool takeeq = iseq && (pose < nties);
    bool ispos  = kk > 0x80000000u;
    bool isneg  = kk < 0x7FFFFFFFu;
    uint32_t off = ispos ? (pbase + (j << 6))
                 : (isneg ? (pbase + (j << 6) + TBL2_W) : (uint32_t)DUMMY_W);
    if (isgt)        sel[wv][posg++]         = off;
    else if (takeeq) sel[wv][total_g + pose] = off;
    cnz_l += ((isgt || takeeq) && (ispos || isneg)) ? 1 : 0;
    pose += iseq;
  }
  // wave-sum of cnz_l (<=16) via bit-serial ballots
  {
    int cnz = 0;
#pragma unroll
    for (int bb = 0; bb < 5; ++bb)
      cnz += (int)__popcll(__ballot((cnz_l >> bb) & 1)) << bb;
    if (lane == 0) partial[wv * BATCHN + b] = cnz;
  }

  // ---- gather: 32 unconditional load+add ----------------------------------
  uint32_t offr[TOPK];
  {
    const uint4* sp = (const uint4*)sel[wv];
#pragma unroll
    for (int q = 0; q < TOPK / 4; ++q) {
      uint4 e4 = sp[q];
      offr[4*q+0] = e4.x; offr[4*q+1] = e4.y;
      offr[4*q+2] = e4.z; offr[4*q+3] = e4.w;
    }
  }
  uint32_t wrd[TOPK];
#pragma unroll
  for (int j = 0; j < TOPK; ++j)
    wrd[j] = tbl[(size_t)offr[j] + lane];
  __builtin_amdgcn_sched_barrier(0);        // keep all 32 loads in flight

  uint32_t acc0 = 0, acc1 = 0, tmp = 0;
  int inch = 0;
#pragma unroll
  for (int j = 0; j < TOPK; ++j) {
    tmp += wrd[j];
    if (++inch == 7 || j == TOPK - 1) {      // <=7 words: 4-bit fields safe
      acc0 += tmp & 0x0F0F0F0Fu;
      acc1 += (tmp >> 4) & 0x0F0F0F0Fu;
      tmp = 0; inch = 0;
    }
  }

  // ---- per-column S = 2*F - 64, scaled ------------------------------------
  const float scale_n = 1.0f / (float)(1 << wv);   // 2^(6-n)*4/256 = 2^-n
#pragma unroll
  for (int i2 = 0; i2 < 4; ++i2) {
    int f0 = (int)((acc0 >> (8 * i2)) & 0xFFu);
    int f1 = (int)((acc1 >> (8 * i2)) & 0xFFu);
    sums[wv][lane + 128 * i2]      = scale_n * (float)(2 * f0 - 64);
    sums[wv][lane + 128 * i2 + 64] = scale_n * (float)(2 * f1 - 64);
  }

  __syncthreads();

  // ---- cumsum over bits, store result[n][b][col] --------------------------
  const int col = threadIdx.x;               // 0..511
  float racc = 0.0f;
  float* obase = out + 8 + (size_t)b * OUTF + col;
#pragma unroll
  for (int n2 = 0; n2 < NBITS; ++n2) {
    racc += sums[n2][col];
    obase[(size_t)n2 * BATCHN * OUTF] = racc;
  }
}

// ---------------------------------------------------------------------------
// finalize: latent_group[n] = (sum_b partial[n][b]) / BATCH
// ---------------------------------------------------------------------------
__global__ __launch_bounds__(512) void fin_kernel(
    const int* __restrict__ partial, float* __restrict__ out)
{
  const int wv   = threadIdx.x >> 6;
  const int lane = threadIdx.x & 63;
  const int* p = partial + wv * BATCHN;
  int s = 0;
#pragma unroll
  for (int k = 0; k < BATCHN / 64; ++k)
    s += p[lane + 64 * k];
#pragma unroll
  for (int d = 32; d >= 1; d >>= 1)
    s += __shfl_down(s, d);
  if (lane == 0) out[wv] = (float)s * (1.0f / (float)BATCHN);
}

extern "C" void kernel_launch(void* const* d_in, const int* in_sizes, int n_in,
                              void* d_out, int out_size, void* d_ws, size_t ws_size,
                              hipStream_t stream)
{
  const float* latent = (const float*)d_in[0];
  const float* W      = (const float*)d_in[1];
  const float* Wm     = (const float*)d_in[2];
  float* out = (float*)d_out;

  int*      partial = (int*)d_ws;                          // 8*4096 ints = 128 KB
  uint32_t* tbl     = (uint32_t*)((char*)d_ws + 131072);   // (2*8192+1)*64 u32 ~ 4.2 MB

  prep_kernel<<<(INF * 64) / 256, 256, 0, stream>>>(W, Wm, tbl);
  main_kernel<<<BATCHN, 512, 0, stream>>>(latent, tbl, out, partial);
  fin_kernel<<<1, 512, 0, stream>>>(partial, out);
}

// Round 4
// 73.404 us; speedup vs baseline: 5.7250x; 1.2274x over previous
//
#include <hip/hip_runtime.h>
#include <stdint.h>

#define NBITS  8
#define SLICE  1024
#define OUTF   512
#define INF    8192
#define TOPK   32
#define BATCHN 4096

#define ROWS    INF                        // 8192 table rows, 64 words each
#define DUMMY_B (ROWS * 64 * 4)            // BYTE offset of dummy row (fields=1)
#define TBL2_B  ((ROWS + 1) * 64 * 4)      // BYTE offset of complement table

// ---------------------------------------------------------------------------
// prep: pack b = (W>=0)+(Wm>=0) in {0,1,2} as 4-bit fields, 8 cols per u32.
// Word w of row r holds columns {w + 64*i}, field i.  Also writes the
// complement table (2-b) and a dummy row of 1-fields (zero contribution).
// ---------------------------------------------------------------------------
__global__ __launch_bounds__(256) void prep_kernel(
    const float* __restrict__ W, const float* __restrict__ Wm,
    uint32_t* __restrict__ tbl)
{
  int tid = blockIdx.x * blockDim.x + threadIdx.x;   // 8192*64 threads
  int r = tid >> 6;        // row 0..8191  (= n*1024 + s)
  int w = tid & 63;        // word 0..63
  const float* wr = W  + (size_t)r * OUTF;
  const float* mr = Wm + (size_t)r * OUTF;
  uint32_t word = 0;
#pragma unroll
  for (int i = 0; i < 8; ++i) {
    int col = w + 64 * i;
    uint32_t b = (wr[col] >= 0.0f ? 1u : 0u) + (mr[col] >= 0.0f ? 1u : 0u);
    word |= b << (4 * i);
  }
  tbl[tid] = word;
  tbl[(TBL2_B / 4) + tid] = 0x22222222u - word;   // fields 2-b (b<=2, no borrow)
  if (tid < 64) tbl[(DUMMY_B / 4) + tid] = 0x11111111u;
}

// ---------------------------------------------------------------------------
// main: one block per batch row, 8 waves; wave n handles bit-slice n.
//  - seeded exact binary search for the top-32 threshold:
//      lo0 = wave-min of lane maxima (>=64 elems >= lo0  =>  k32 >= lo0)
//      hi0 = wave-max of lane maxima (= global max >= k32)
//    early exit when count==32 (then the >=mid set IS the top-k, no ties).
//  - selection: single predicated LDS write of sign-folded BYTE offsets.
//  - gather: 32 unconditional load+add (uniform base + small v_add).
//  - per-column S = 2*field_sum - 64, cumsum over bits via LDS, store.
// ---------------------------------------------------------------------------
__global__ __launch_bounds__(512, 4) void main_kernel(
    const float* __restrict__ latent,
    const uint32_t* __restrict__ tbl,
    float* __restrict__ out, int* __restrict__ partial)
{
  __shared__ __align__(16) uint32_t sel[NBITS][TOPK];   // BYTE offsets into tbl
  __shared__ float sums[NBITS][OUTF];

  const int b    = blockIdx.x;
  const int wv   = threadIdx.x >> 6;        // bit index n
  const int lane = threadIdx.x & 63;

  // ---- load 16 contiguous values, map to sortable keys, track lane max ----
  const float4* src =
      (const float4*)(latent + (size_t)b * INF + (size_t)wv * SLICE + lane * 16);
  uint32_t key[16];
  uint32_t lmax = 0u;
#pragma unroll
  for (int q = 0; q < 4; ++q) {
    float4 f = src[q];
    float vv[4] = {f.x, f.y, f.z, f.w};
#pragma unroll
    for (int t = 0; t < 4; ++t) {
      uint32_t u = __float_as_uint(vv[t]);
      uint32_t m = ((uint32_t)((int32_t)u >> 31)) | 0x80000000u;
      uint32_t k = u ^ m;                    // monotone total order
      key[4*q+t] = k;
      lmax = lmax > k ? lmax : k;
    }
  }
  // sign from key:  v>0 <=> key>0x80000000 ; v<0 <=> key<0x7FFFFFFF

  // ---- seeded bounds (valid for ANY input) --------------------------------
  uint32_t bmin = lmax, bmax = lmax;
#pragma unroll
  for (int d = 1; d < 64; d <<= 1) {
    uint32_t tn = (uint32_t)__shfl_xor((int)bmin, d);
    uint32_t tx = (uint32_t)__shfl_xor((int)bmax, d);
    bmin = bmin < tn ? bmin : tn;
    bmax = bmax > tx ? bmax : tx;
  }

  // ---- binary search for threshold (exact, early-exit) --------------------
  uint32_t T;
  {
    uint32_t lo = bmin, hi = bmax;
    bool done = false;
    while (lo < hi) {
      uint32_t d   = hi - lo;
      uint32_t mid = lo + (d >> 1) + (d & 1u);   // upper mid
      uint32_t c = 0;
#pragma unroll
      for (int j = 0; j < 16; ++j) c += (key[j] >= mid) ? 1u : 0u;
      int cnt = 0;
#pragma unroll
      for (int bb = 0; bb < 5; ++bb)
        cnt += (int)__popcll(__ballot((c >> bb) & 1u)) << bb;
      if (cnt == TOPK) { T = mid - 1u; done = true; break; }  // exact set
      if (cnt > TOPK) lo = mid; else hi = mid - 1u;
    }
    if (!done) T = lo;
  }

  // ---- counts + stable (lowest-index-first) tie positions -----------------
  int cgt = 0, ceq = 0;
#pragma unroll
  for (int j = 0; j < 16; ++j) { cgt += (key[j] > T); ceq += (key[j] == T); }
  int packed = (cgt << 16) | ceq;
  int sc = packed;
#pragma unroll
  for (int dd = 1; dd < 64; dd <<= 1) {
    int t = __shfl_up(sc, dd);
    if (lane >= dd) sc += t;
  }
  int tot     = __shfl(sc, 63);
  int total_g = tot >> 16;                 // # strictly greater than T (<=32)
  int nties   = TOPK - total_g;            // ties to take, lowest index first
  int excl    = sc - packed;
  int posg    = excl >> 16;
  int pose    = excl & 0xFFFF;

  // ---- selection: one predicated LDS write of sign-folded byte offsets ----
  const uint32_t pbase = ((uint32_t)(wv * SLICE + lane * 16)) << 8;  // row*256
  int cnz_l = 0;
#pragma unroll
  for (int j = 0; j < 16; ++j) {
    uint32_t kk  = key[j];
    bool isgt    = kk > T;
    bool iseq    = (kk == T);
    bool takeeq  = iseq && (pose < nties);
    bool take    = isgt || takeeq;
    bool ispos   = kk > 0x80000000u;
    bool isneg   = kk < 0x7FFFFFFFu;
    uint32_t off = ispos ? (pbase + (j << 8))
                 : (isneg ? (pbase + (j << 8) + TBL2_B) : (uint32_t)DUMMY_B);
    int slot = isgt ? posg : (total_g + pose);
    if (take) sel[wv][slot] = off;
    posg += isgt ? 1 : 0;
    pose += iseq ? 1 : 0;
    cnz_l += (take && (ispos || isneg)) ? 1 : 0;
  }
  // wave-sum of cnz_l (<=16) via bit-serial ballots
  {
    int cnz = 0;
#pragma unroll
    for (int bb = 0; bb < 5; ++bb)
      cnz += (int)__popcll(__ballot((cnz_l >> bb) & 1)) << bb;
    if (lane == 0) partial[wv * BATCHN + b] = cnz;
  }

  // ---- gather: 32 unconditional load+add ----------------------------------
  uint32_t offr[TOPK];
  {
    const uint4* sp = (const uint4*)sel[wv];
#pragma unroll
    for (int q = 0; q < TOPK / 4; ++q) {
      uint4 e4 = sp[q];
      offr[4*q+0] = e4.x; offr[4*q+1] = e4.y;
      offr[4*q+2] = e4.z; offr[4*q+3] = e4.w;
    }
  }
  const uint32_t lb = (uint32_t)lane << 2;
  const char* tbase = (const char*)tbl;
  uint32_t wrd[TOPK];
#pragma unroll
  for (int j = 0; j < TOPK; ++j)
    wrd[j] = *(const uint32_t*)(tbase + (offr[j] + lb));
  __builtin_amdgcn_sched_barrier(0);        // keep all 32 loads in flight

  uint32_t acc0 = 0, acc1 = 0, tmp = 0;
  int inch = 0;
#pragma unroll
  for (int j = 0; j < TOPK; ++j) {
    tmp += wrd[j];
    if (++inch == 7 || j == TOPK - 1) {      // <=7 words: 4-bit fields safe
      acc0 += tmp & 0x0F0F0F0Fu;
      acc1 += (tmp >> 4) & 0x0F0F0F0Fu;
      tmp = 0; inch = 0;
    }
  }

  // ---- per-column S = 2*F - 64, scaled ------------------------------------
  const float scale_n = 1.0f / (float)(1 << wv);   // 2^(6-n)*4/256 = 2^-n
#pragma unroll
  for (int i2 = 0; i2 < 4; ++i2) {
    int f0 = (int)((acc0 >> (8 * i2)) & 0xFFu);
    int f1 = (int)((acc1 >> (8 * i2)) & 0xFFu);
    sums[wv][lane + 128 * i2]      = scale_n * (float)(2 * f0 - 64);
    sums[wv][lane + 128 * i2 + 64] = scale_n * (float)(2 * f1 - 64);
  }

  __syncthreads();

  // ---- cumsum over bits, store result[n][b][col] --------------------------
  const int col = threadIdx.x;               // 0..511
  float racc = 0.0f;
  float* obase = out + 8 + (size_t)b * OUTF + col;
#pragma unroll
  for (int n2 = 0; n2 < NBITS; ++n2) {
    racc += sums[n2][col];
    obase[(size_t)n2 * BATCHN * OUTF] = racc;
  }
}

// ---------------------------------------------------------------------------
// finalize: latent_group[n] = (sum_b partial[n][b]) / BATCH
// ---------------------------------------------------------------------------
__global__ __launch_bounds__(512) void fin_kernel(
    const int* __restrict__ partial, float* __restrict__ out)
{
  const int wv   = threadIdx.x >> 6;
  const int lane = threadIdx.x & 63;
  const int* p = partial + wv * BATCHN;
  int s = 0;
#pragma unroll
  for (int k = 0; k < BATCHN / 64; ++k)
    s += p[lane + 64 * k];
#pragma unroll
  for (int d = 32; d >= 1; d >>= 1)
    s += __shfl_down(s, d);
  if (lane == 0) out[wv] = (float)s * (1.0f / (float)BATCHN);
}

extern "C" void kernel_launch(void* const* d_in, const int* in_sizes, int n_in,
                              void* d_out, int out_size, void* d_ws, size_t ws_size,
                              hipStream_t stream)
{
  const float* latent = (const float*)d_in[0];
  const float* W      = (const float*)d_in[1];
  const float* Wm     = (const float*)d_in[2];
  float* out = (float*)d_out;

  int*      partial = (int*)d_ws;                          // 8*4096 ints = 128 KB
  uint32_t* tbl     = (uint32_t*)((char*)d_ws + 131072);   // ~4.2 MB tables

  prep_kernel<<<(INF * 64) / 256, 256, 0, stream>>>(W, Wm, tbl);
  main_kernel<<<BATCHN, 512, 0, stream>>>(latent, tbl, out, partial);
  fin_kernel<<<1, 512, 0, stream>>>(partial, out);
}

// Round 5
// 70.990 us; speedup vs baseline: 5.9198x; 1.0340x over previous
//
#include <hip/hip_runtime.h>
#include <stdint.h>

#define NBITS  8
#define SLICE  1024
#define OUTF   512
#define INF    8192
#define TOPK   32
#define BATCHN 4096

#define ROWS    INF                        // 8192 table rows, 64 words each
#define DUMMY_B (ROWS * 64 * 4)            // BYTE offset of dummy row (fields=1)
#define TBL2_B  ((ROWS + 1) * 64 * 4)      // BYTE offset of complement table

// monotone float<->sortable-key bijection
__device__ __forceinline__ uint32_t fkey_u(uint32_t u) {
  uint32_t m = ((uint32_t)((int32_t)u >> 31)) | 0x80000000u;
  return u ^ m;
}
__device__ __forceinline__ float kfloat(uint32_t k) {
  uint32_t u = (k & 0x80000000u) ? (k ^ 0x80000000u) : ~k;
  return __uint_as_float(u);
}

// ---------------------------------------------------------------------------
// prep: pack b = (W>=0)+(Wm>=0) in {0,1,2} as 4-bit fields, 8 cols per u32.
// Word w of row r holds columns {w + 64*i}, field i.  Also writes the
// complement table (2-b) and a dummy row of 1-fields (zero contribution).
// ---------------------------------------------------------------------------
__global__ __launch_bounds__(256) void prep_kernel(
    const float* __restrict__ W, const float* __restrict__ Wm,
    uint32_t* __restrict__ tbl)
{
  int tid = blockIdx.x * blockDim.x + threadIdx.x;   // 8192*64 threads
  int r = tid >> 6;        // row 0..8191  (= n*1024 + s)
  int w = tid & 63;        // word 0..63
  const float* wr = W  + (size_t)r * OUTF;
  const float* mr = Wm + (size_t)r * OUTF;
  uint32_t word = 0;
#pragma unroll
  for (int i = 0; i < 8; ++i) {
    int col = w + 64 * i;
    uint32_t b = (wr[col] >= 0.0f ? 1u : 0u) + (mr[col] >= 0.0f ? 1u : 0u);
    word |= b << (4 * i);
  }
  tbl[tid] = word;
  tbl[(TBL2_B / 4) + tid] = 0x22222222u - word;   // fields 2-b (b<=2, no borrow)
  if (tid < 64) tbl[(DUMMY_B / 4) + tid] = 0x11111111u;
}

// ---------------------------------------------------------------------------
// main: one block per batch row, 8 waves; wave n handles bit-slice n.
//  - exact top-32 threshold search with VALUE-SPACE probes (float midpoint,
//    validated against the integer bracket; integer upper-mid fallback keeps
//    the worst case bounded).  Early exit when count==32: the >=mid set IS
//    the exact top-k (a boundary tie provably prevents cnt==32).
//  - fast path: single scan of per-lane take count, cmp+write selection.
//  - fallback (ties / no early exit): full stable lowest-index-first logic.
//  - gather: 32 unconditional load+add of sign-folded table rows.
//  - per-column S = 2*field_sum - 64, cumsum over bits via LDS, store.
// ---------------------------------------------------------------------------
__global__ __launch_bounds__(512, 4) void main_kernel(
    const float* __restrict__ latent,
    const uint32_t* __restrict__ tbl,
    float* __restrict__ out, int* __restrict__ partial)
{
  __shared__ __align__(16) uint32_t sel[NBITS][TOPK];   // BYTE offsets into tbl
  __shared__ float sums[NBITS][OUTF];

  const int b    = blockIdx.x;
  const int wv   = threadIdx.x >> 6;        // bit index n
  const int lane = threadIdx.x & 63;

  // ---- load 16 contiguous values, map to sortable keys, track lane max ----
  const float4* src =
      (const float4*)(latent + (size_t)b * INF + (size_t)wv * SLICE + lane * 16);
  uint32_t key[16];
  uint32_t lmax = 0u;
#pragma unroll
  for (int q = 0; q < 4; ++q) {
    float4 f = src[q];
    float vv[4] = {f.x, f.y, f.z, f.w};
#pragma unroll
    for (int t = 0; t < 4; ++t) {
      uint32_t k = fkey_u(__float_as_uint(vv[t]));
      key[4*q+t] = k;
      lmax = lmax > k ? lmax : k;
    }
  }
  // sign from key:  v>0 <=> key>0x80000000 ; v<0 <=> key<0x7FFFFFFF

  // ---- seeded bounds (valid for ANY input) --------------------------------
  // bmin = wave-min of lane maxima: >=64 elements >= bmin  =>  T >= bmin.
  // bmax = wave-max = global max >= T.
  uint32_t bmin = lmax, bmax = lmax;
#pragma unroll
  for (int d = 1; d < 64; d <<= 1) {
    uint32_t tn = (uint32_t)__shfl_xor((int)bmin, d);
    uint32_t tx = (uint32_t)__shfl_xor((int)bmax, d);
    bmin = bmin < tn ? bmin : tn;
    bmax = bmax > tx ? bmax : tx;
  }

  // ---- threshold search: value-space probes, exact bracket ----------------
  uint32_t T = 0, midE = 0, cE = 0;
  bool fast = false;
  {
    uint32_t lo = bmin, hi = bmax;
    while (lo < hi) {
      uint32_t d   = hi - lo;
      uint32_t mid = lo + (d >> 1) + (d & 1u);         // int upper-mid fallback
      float fm     = 0.5f * (kfloat(lo) + kfloat(hi)); // value-space midpoint
      uint32_t km  = fkey_u(__float_as_uint(fm));
      if (km > lo && km <= hi) mid = km;               // validated probe
      uint32_t c = 0;
#pragma unroll
      for (int j = 0; j < 16; ++j) c += (key[j] >= mid) ? 1u : 0u;
      int cnt = 0;
#pragma unroll
      for (int bb = 0; bb < 5; ++bb)
        cnt += (int)__popcll(__ballot((c >> bb) & 1u)) << bb;
      if (cnt == TOPK) { fast = true; midE = mid; cE = c; break; }
      if (cnt > TOPK) lo = mid; else hi = mid - 1u;
    }
    if (!fast) T = lo;
  }

  const uint32_t pbase = ((uint32_t)(wv * SLICE + lane * 16)) << 8;  // row*256
  int nzl = 0;                               // per-lane taken-nonzero count

  if (fast) {
    // ---- fast path: take set is exactly {key >= midE}, no ties ------------
    int sc = (int)cE;
#pragma unroll
    for (int dd = 1; dd < 64; dd <<= 1) {
      int t = __shfl_up(sc, dd);
      if (lane >= dd) sc += t;
    }
    int slot = sc - (int)cE;                 // exclusive prefix of take counts
#pragma unroll
    for (int j = 0; j < 16; ++j) {
      uint32_t kk = key[j];
      if (kk >= midE) {
        bool ispos = kk > 0x80000000u;
        bool isneg = kk < 0x7FFFFFFFu;
        uint32_t off = ispos ? (pbase + (j << 8))
                     : (isneg ? (pbase + (j << 8) + TBL2_B) : (uint32_t)DUMMY_B);
        sel[wv][slot++] = off;
        nzl += (ispos || isneg) ? 1 : 0;
      }
    }
  } else {
    // ---- fallback: stable lowest-index-first tie handling -----------------
    int cgt = 0, ceq = 0;
#pragma unroll
    for (int j = 0; j < 16; ++j) { cgt += (key[j] > T); ceq += (key[j] == T); }
    int packed = (cgt << 16) | ceq;
    int sc = packed;
#pragma unroll
    for (int dd = 1; dd < 64; dd <<= 1) {
      int t = __shfl_up(sc, dd);
      if (lane >= dd) sc += t;
    }
    int tot     = __shfl(sc, 63);
    int total_g = tot >> 16;                 // # strictly greater than T
    int nties   = TOPK - total_g;            // ties to take, lowest index first
    int excl    = sc - packed;
    int posg    = excl >> 16;
    int pose    = excl & 0xFFFF;
#pragma unroll
    for (int j = 0; j < 16; ++j) {
      uint32_t kk  = key[j];
      bool isgt    = kk > T;
      bool iseq    = (kk == T);
      bool takeeq  = iseq && (pose < nties);
      bool take    = isgt || takeeq;
      bool ispos   = kk > 0x80000000u;
      bool isneg   = kk < 0x7FFFFFFFu;
      uint32_t off = ispos ? (pbase + (j << 8))
                   : (isneg ? (pbase + (j << 8) + TBL2_B) : (uint32_t)DUMMY_B);
      int slot = isgt ? posg : (total_g + pose);
      if (take) sel[wv][slot] = off;
      posg += isgt ? 1 : 0;
      pose += iseq ? 1 : 0;
      nzl  += (take && (ispos || isneg)) ? 1 : 0;
    }
  }

  // wave-sum of nzl (<=16) via bit-serial ballots
  {
    int cnz = 0;
#pragma unroll
    for (int bb = 0; bb < 5; ++bb)
      cnz += (int)__popcll(__ballot((nzl >> bb) & 1)) << bb;
    if (lane == 0) partial[wv * BATCHN + b] = cnz;
  }

  // ---- gather: 32 unconditional load+add ----------------------------------
  uint32_t offr[TOPK];
  {
    const uint4* sp = (const uint4*)sel[wv];
#pragma unroll
    for (int q = 0; q < TOPK / 4; ++q) {
      uint4 e4 = sp[q];
      offr[4*q+0] = e4.x; offr[4*q+1] = e4.y;
      offr[4*q+2] = e4.z; offr[4*q+3] = e4.w;
    }
  }
  const uint32_t lb = (uint32_t)lane << 2;
  const char* tbase = (const char*)tbl;
  uint32_t wrd[TOPK];
#pragma unroll
  for (int j = 0; j < TOPK; ++j)
    wrd[j] = *(const uint32_t*)(tbase + (offr[j] + lb));
  __builtin_amdgcn_sched_barrier(0);        // keep the gather loads in flight

  uint32_t acc0 = 0, acc1 = 0, tmp = 0;
  int inch = 0;
#pragma unroll
  for (int j = 0; j < TOPK; ++j) {
    tmp += wrd[j];
    if (++inch == 7 || j == TOPK - 1) {      // <=7 words: 4-bit fields safe
      acc0 += tmp & 0x0F0F0F0Fu;
      acc1 += (tmp >> 4) & 0x0F0F0F0Fu;
      tmp = 0; inch = 0;
    }
  }

  // ---- per-column S = 2*F - 64, scaled ------------------------------------
  const float scale_n = 1.0f / (float)(1 << wv);   // 2^(6-n)*4/256 = 2^-n
#pragma unroll
  for (int i2 = 0; i2 < 4; ++i2) {
    int f0 = (int)((acc0 >> (8 * i2)) & 0xFFu);
    int f1 = (int)((acc1 >> (8 * i2)) & 0xFFu);
    sums[wv][lane + 128 * i2]      = scale_n * (float)(2 * f0 - 64);
    sums[wv][lane + 128 * i2 + 64] = scale_n * (float)(2 * f1 - 64);
  }

  __syncthreads();

  // ---- cumsum over bits, store result[n][b][col] --------------------------
  const int col = threadIdx.x;               // 0..511
  float racc = 0.0f;
  float* obase = out + 8 + (size_t)b * OUTF + col;
#pragma unroll
  for (int n2 = 0; n2 < NBITS; ++n2) {
    racc += sums[n2][col];
    obase[(size_t)n2 * BATCHN * OUTF] = racc;
  }
}

// ---------------------------------------------------------------------------
// finalize: latent_group[n] = (sum_b partial[n][b]) / BATCH
// ---------------------------------------------------------------------------
__global__ __launch_bounds__(512) void fin_kernel(
    const int* __restrict__ partial, float* __restrict__ out)
{
  const int wv   = threadIdx.x >> 6;
  const int lane = threadIdx.x & 63;
  const int* p = partial + wv * BATCHN;
  int s = 0;
#pragma unroll
  for (int k = 0; k < BATCHN / 64; ++k)
    s += p[lane + 64 * k];
#pragma unroll
  for (int d = 32; d >= 1; d >>= 1)
    s += __shfl_down(s, d);
  if (lane == 0) out[wv] = (float)s * (1.0f / (float)BATCHN);
}

extern "C" void kernel_launch(void* const* d_in, const int* in_sizes, int n_in,
                              void* d_out, int out_size, void* d_ws, size_t ws_size,
                              hipStream_t stream)
{
  const float* latent = (const float*)d_in[0];
  const float* W      = (const float*)d_in[1];
  const float* Wm     = (const float*)d_in[2];
  float* out = (float*)d_out;

  int*      partial = (int*)d_ws;                          // 8*4096 ints = 128 KB
  uint32_t* tbl     = (uint32_t*)((char*)d_ws + 131072);   // ~4.2 MB tables

  prep_kernel<<<(INF * 64) / 256, 256, 0, stream>>>(W, Wm, tbl);
  main_kernel<<<BATCHN, 512, 0, stream>>>(latent, tbl, out, partial);
  fin_kernel<<<1, 512, 0, stream>>>(partial, out);
}